// Round 4
// baseline (295.067 us; speedup 1.0000x reference)
//
#include <hip/hip_runtime.h>

typedef __bf16 bf16;
typedef __bf16 bf16x8 __attribute__((ext_vector_type(8)));
typedef float floatx4 __attribute__((ext_vector_type(4)));

#define IN_F  1024
#define OUT_F 4096
#define M_DIM 8192   // 16*512
#define K_DIM 1024
#define N_DIM 4096

__device__ __forceinline__ unsigned short f2bf(float f) {
    unsigned int u = __float_as_uint(f);
    u += 0x7FFFu + ((u >> 16) & 1u);   // round-to-nearest-even
    return (unsigned short)(u >> 16);
}

// ---------------------------------------------------------------------------
// Kernel 1: build effective weight W' (bf16, row-major [OUT_F][IN_F] = B^T)
// (unchanged from R3 — LDS-staged, rotation keeps conflicts <=2-way)
// ---------------------------------------------------------------------------
__global__ __launch_bounds__(256) void build_w_kernel(
    const float* __restrict__ W, const float* __restrict__ alphas,
    unsigned short* __restrict__ Wb)
{
    __shared__ float Wl[16 * 256];   // 16 KB

    const int t = threadIdx.x;
    const int rb = blockIdx.x >> 2;      // 256 row-blocks
    const int cb = blockIdx.x & 3;       // 4 col-blocks
    const int row0 = rb * 16, col0 = cb * 256;

    const float4* src = (const float4*)(W + (size_t)row0 * IN_F + col0);
    #pragma unroll
    for (int j = 0; j < 4; ++j) {
        const int idx = j * 256 + t;          // 0..1023 float4s
        const int r = idx >> 6, c4 = idx & 63;
        ((float4*)Wl)[r * 64 + c4] = src[(size_t)r * 256 + c4];
    }

    float av[5];
    float mx = -1e30f;
    #pragma unroll
    for (int j = 0; j < 5; ++j) { av[j] = alphas[j]; mx = fmaxf(mx, av[j]); }
    float s = 0.f;
    #pragma unroll
    for (int j = 0; j < 5; ++j) { av[j] = __expf(av[j] - mx); s += av[j]; }
    const float inv = 1.f / s;
    #pragma unroll
    for (int j = 0; j < 5; ++j) av[j] *= inv;

    __syncthreads();

    const int k  = t >> 4;
    const int jj = t & 15;
    unsigned short ov[16];

    #pragma unroll
    for (int jb = 0; jb < 16; ++jb) {
        const int jr = (jb + k) & 15;
        const int j  = jr * 16 + jj;
        float acc = av[0] * Wl[k * 256 + j];
        #pragma unroll
        for (int e = 1; e <= 4; ++e) {
            const int bs   = 1 << e;
            const int mask = bs - 1;
            const int ol = k & ~mask;
            const int il = j & ~mask;
            const int d  = (k - j) & mask;
            float ssum = 0.f;
            #pragma unroll
            for (int r = 0; r < bs; ++r)
                ssum += Wl[(ol + r) * 256 + il + ((r + d) & mask)];
            acc += av[e] * (1.0f / (float)bs) * ssum;
        }
        ov[jb] = f2bf(acc);
    }

    __syncthreads();
    unsigned short* Wls = (unsigned short*)Wl;
    #pragma unroll
    for (int jb = 0; jb < 16; ++jb) {
        const int jr = (jb + k) & 15;
        Wls[k * 256 + jr * 16 + jj] = ov[jb];
    }
    __syncthreads();

    const int kr = t >> 4, cg = t & 15;
    const uint4* p = (const uint4*)(Wls + kr * 256 + cg * 16);
    uint4* dst = (uint4*)(Wb + (size_t)(row0 + kr) * IN_F + col0 + cg * 16);
    dst[0] = p[0];
    dst[1] = p[1];
}

// ---------------------------------------------------------------------------
// Kernel 2: x f32 -> bf16, 8 elements/thread
// ---------------------------------------------------------------------------
__global__ __launch_bounds__(256) void cvt_x_kernel(
    const float* __restrict__ x, uint4* __restrict__ xb)
{
    const int t = blockIdx.x * 256 + threadIdx.x;
    const float4* xv = (const float4*)x;
    const float4 v0 = xv[2 * t];
    const float4 v1 = xv[2 * t + 1];
    uint4 o;
    o.x = (unsigned)f2bf(v0.x) | ((unsigned)f2bf(v0.y) << 16);
    o.y = (unsigned)f2bf(v0.z) | ((unsigned)f2bf(v0.w) << 16);
    o.z = (unsigned)f2bf(v1.x) | ((unsigned)f2bf(v1.y) << 16);
    o.w = (unsigned)f2bf(v1.z) | ((unsigned)f2bf(v1.w) << 16);
    xb[t] = o;
}

// ---------------------------------------------------------------------------
// Kernel 3: C[M][N] = A[M][K] * B[N][K]^T + bias
// Block 256x128, 4 waves, wave tile 64x128 (4x8 of 16x16x32 MFMA).
// Software-pipelined K-loop, ONE barrier/iter:
//   - B(kt+1): buffer_load -> VGPR (breg) at iter top, ds_write at iter end
//     -> global latency hidden under MFMA(kt), LDS dbuf (2x16KB).
//   - A(kt+1): global->VGPR reload into dead af regs mid/late iter; stays
//     in flight across raw s_barrier (no vmcnt(0) drain; compiler inserts
//     precise per-register vmcnt at first MFMA use).
//   - barrier = "s_waitcnt lgkmcnt(0); s_barrier" (own ds_writes landed;
//     all waves' writes complete before any wave reads next buffer).
// ---------------------------------------------------------------------------
__global__ __launch_bounds__(256, 2) void gemm_bt_kernel(
    const bf16* __restrict__ A, const bf16* __restrict__ B,
    const float* __restrict__ bias, float* __restrict__ C)
{
    constexpr int N = N_DIM, K = K_DIM;
    constexpr int TM = 256, TN = 128, TK = 64;

    __shared__ __align__(16) bf16 Bs[2 * TN * TK];   // 32 KB double buffer

    const int t    = threadIdx.x;
    const int w    = t >> 6;
    const int l    = t & 63;
    const int quad = l >> 4;
    const int l16  = l & 15;
    const int x7   = l16 & 7;

    const int nb = N / TN;                 // 32
    const int bm = blockIdx.x / nb;
    const int bn = blockIdx.x % nb;
    const int wm = w * 64;

    floatx4 acc[4][8] = {};

    // B staging: chunk c = q*256+t: row = c>>3, kc = c&7 (straight source);
    // LDS dest slot = kc ^ (row&7)  -> fragment reads conflict-free.
    const bf16* Bp[4];
    int wdst[4];
    #pragma unroll
    for (int q = 0; q < 4; ++q) {
        const int chunk = q * 256 + t;
        const int row = chunk >> 3, kc = chunk & 7;
        Bp[q]   = B + (size_t)(bn * TN + row) * K + kc * 8;
        wdst[q] = row * TK + (kc ^ (row & 7)) * 8;
    }

    // A fragment base: lane (l16, quad) of wave-row-group mt
    const bf16* Ap = A + (size_t)(bm * TM + wm + l16) * K + quad * 8;

    bf16x8 af0[4], af1[4];
    uint4 breg[4];

    // ---- prologue: stage B(0), load A(0) ----
    #pragma unroll
    for (int q = 0; q < 4; ++q) breg[q] = *(const uint4*)(Bp[q]);
    #pragma unroll
    for (int mt = 0; mt < 4; ++mt)
        af0[mt] = *(const bf16x8*)(Ap + (size_t)mt * 16 * K);
    #pragma unroll
    for (int mt = 0; mt < 4; ++mt)
        af1[mt] = *(const bf16x8*)(Ap + (size_t)mt * 16 * K + 32);
    #pragma unroll
    for (int q = 0; q < 4; ++q) *(uint4*)(Bs + wdst[q]) = breg[q];
    asm volatile("s_waitcnt lgkmcnt(0)\ns_barrier" ::: "memory");

    const bf16* bs_r = Bs;
    bf16* bs_w = Bs + TN * TK;

    #pragma unroll 1
    for (int kt = 0; kt < K; kt += TK) {
        const bool nl = (kt + TK) < K;

        // prefetch next B tile into registers (hidden under MFMA below)
        if (nl) {
            #pragma unroll
            for (int q = 0; q < 4; ++q)
                breg[q] = *(const uint4*)(Bp[q] + kt + TK);
        }

        // ---- ks = 0 ----
        {
            bf16x8 bfr[8];
            const int kx = (quad ^ x7) * 8;
            #pragma unroll
            for (int nt = 0; nt < 8; ++nt)
                bfr[nt] = *(const bf16x8*)(bs_r + (nt * 16 + l16) * TK + kx);
            #pragma unroll
            for (int mt = 0; mt < 4; ++mt)
                #pragma unroll
                for (int nt = 0; nt < 8; ++nt)
                    acc[mt][nt] = __builtin_amdgcn_mfma_f32_16x16x32_bf16(
                        af0[mt], bfr[nt], acc[mt][nt], 0, 0, 0);
        }
        // af0 now dead: prefetch A(kt+1) ks0 half
        if (nl) {
            #pragma unroll
            for (int mt = 0; mt < 4; ++mt)
                af0[mt] = *(const bf16x8*)(Ap + (size_t)mt * 16 * K + kt + TK);
        }

        // ---- ks = 1 ----
        {
            bf16x8 bfr[8];
            const int kx = ((4 + quad) ^ x7) * 8;
            #pragma unroll
            for (int nt = 0; nt < 8; ++nt)
                bfr[nt] = *(const bf16x8*)(bs_r + (nt * 16 + l16) * TK + kx);
            #pragma unroll
            for (int mt = 0; mt < 4; ++mt)
                #pragma unroll
                for (int nt = 0; nt < 8; ++nt)
                    acc[mt][nt] = __builtin_amdgcn_mfma_f32_16x16x32_bf16(
                        af1[mt], bfr[nt], acc[mt][nt], 0, 0, 0);
        }
        // af1 dead: prefetch A(kt+1) ks1 half; commit breg to other LDS buffer
        if (nl) {
            #pragma unroll
            for (int mt = 0; mt < 4; ++mt)
                af1[mt] = *(const bf16x8*)(Ap + (size_t)mt * 16 * K + kt + TK + 32);
            #pragma unroll
            for (int q = 0; q < 4; ++q)
                *(uint4*)(bs_w + wdst[q]) = breg[q];
        }

        asm volatile("s_waitcnt lgkmcnt(0)\ns_barrier" ::: "memory");
        const bf16* tmp = bs_r; bs_r = bs_w; bs_w = (bf16*)tmp;
    }

    // epilogue: C/D layout col = lane&15, row = quad*4 + reg  (m89-verified)
    float bv[8];
    #pragma unroll
    for (int nt = 0; nt < 8; ++nt)
        bv[nt] = bias[bn * TN + nt * 16 + l16];

    float* Cbase = C + (size_t)(bm * TM + wm) * N + bn * TN;
    #pragma unroll
    for (int mt = 0; mt < 4; ++mt) {
        #pragma unroll
        for (int r = 0; r < 4; ++r) {
            float* crowp = Cbase + (size_t)(mt * 16 + quad * 4 + r) * N;
            #pragma unroll
            for (int nt = 0; nt < 8; ++nt)
                crowp[nt * 16 + l16] = acc[mt][nt][r] + bv[nt];
        }
    }
}

// ---------------------------------------------------------------------------
extern "C" void kernel_launch(void* const* d_in, const int* in_sizes, int n_in,
                              void* d_out, int out_size, void* d_ws, size_t ws_size,
                              hipStream_t stream) {
    const float* x      = (const float*)d_in[0];   // [16,512,1024]
    const float* weight = (const float*)d_in[1];   // [4096,1024]
    const float* alphas = (const float*)d_in[2];   // [5]
    const float* bias   = (const float*)d_in[3];   // [4096]
    float* out = (float*)d_out;                    // [16,512,4096] f32

    // workspace: Wb (bf16, 8 MB) | Xb (bf16, 16 MB)
    unsigned short* Wb = (unsigned short*)d_ws;
    unsigned short* Xb = (unsigned short*)((char*)d_ws + (size_t)OUT_F * IN_F * 2);

    build_w_kernel<<<(OUT_F / 16) * (IN_F / 256), 256, 0, stream>>>(weight, alphas, Wb);
    cvt_x_kernel<<<(M_DIM * K_DIM / 8) / 256, 256, 0, stream>>>(x, (uint4*)Xb);

    const int grid = (M_DIM / 256) * (N_DIM / 128);   // 32*32 = 1024 blocks
    gemm_bt_kernel<<<grid, 256, 0, stream>>>((const bf16*)Xb, (const bf16*)Wb, bias, out);
}